// Round 10
// baseline (87.803 us; speedup 1.0000x reference)
//
#include <hip/hip_runtime.h>

// ---------------------------------------------------------------------------
// MHSA fused block, MI355X (gfx950).
// fold(BN->W, fp16, q-rows pre-scaled by log2e) -> pos table (fp16) ->
// QKV projection GEMM (fp16 MFMA, BK=32 double-buffered single-barrier
// pipeline: A via gload_lds, B via issue-early/write-late reg staging) ->
// flash attention (8-wave blocks, exp2 softmax, l-sum via ones-MFMA,
// dbuf gload_lds pipeline, XCD-local L2 reuse).
// ---------------------------------------------------------------------------

typedef _Float16 f16x8 __attribute__((ext_vector_type(8)));
typedef __attribute__((ext_vector_type(4))) float f32x4;
typedef __attribute__((ext_vector_type(4))) unsigned int u32x4;
typedef __attribute__((ext_vector_type(2))) unsigned int u32x2;

#define MFMAH(a, b, c) __builtin_amdgcn_mfma_f32_16x16x32_f16(a, b, c, 0, 0, 0)
#define LOG2E 1.4426950408889634f

__device__ __forceinline__ unsigned pkh(float a, float b) {
  auto p = __builtin_amdgcn_cvt_pkrtz(a, b);  // __fp16 ext_vector(2)
  return __builtin_bit_cast(unsigned, p);
}
__device__ __forceinline__ short f2h(float a) {
  _Float16 h = (_Float16)a;
  return __builtin_bit_cast(short, h);
}
__device__ __forceinline__ int sfn(int x) { return (x & 3) ^ ((x >> 2) & 3); }

// 16B global -> LDS direct (wave-uniform LDS base + lane*16)
__device__ __forceinline__ void gload16(const void* g, void* l) {
  __builtin_amdgcn_global_load_lds(
      (const __attribute__((address_space(1))) void*)g,
      (__attribute__((address_space(3))) void*)l, 16, 0, 0);
}

// ---------------------------------------------------------------------------
// Fold BN into conv weights -> fp16. Wh[768][512] (rows: 128 q, 128 k, 512 v).
// q rows (and q bias) pre-scaled by log2e so softmax runs in exp2 domain.
// ---------------------------------------------------------------------------
__global__ __launch_bounds__(256) void fold_kernel(
    const float* __restrict__ Wq, const float* __restrict__ bq,
    const float* __restrict__ qg, const float* __restrict__ qbe,
    const float* __restrict__ qme, const float* __restrict__ qva,
    const float* __restrict__ Wk, const float* __restrict__ bk,
    const float* __restrict__ kg, const float* __restrict__ kbe,
    const float* __restrict__ kme, const float* __restrict__ kva,
    const float* __restrict__ Wv, const float* __restrict__ bv,
    const float* __restrict__ vg, const float* __restrict__ vbe,
    const float* __restrict__ vme, const float* __restrict__ vva,
    unsigned short* __restrict__ Wh, float* __restrict__ bfv)
{
  int idx = blockIdx.x * 256 + threadIdx.x;
  if (idx >= 768 * 512) return;
  int o = idx >> 9, c = idx & 511;
  float w, sc, bb, mean, beta, post;
  if (o < 128) {
    sc = qg[o] / sqrtf(qva[o] + 1e-5f);
    w = Wq[o * 512 + c]; bb = bq[o]; mean = qme[o]; beta = qbe[o];
    post = LOG2E;
  } else if (o < 256) {
    int r = o - 128;
    sc = kg[r] / sqrtf(kva[r] + 1e-5f);
    w = Wk[r * 512 + c]; bb = bk[r]; mean = kme[r]; beta = kbe[r];
    post = 1.0f;
  } else {
    int r = o - 256;
    sc = vg[r] / sqrtf(vva[r] + 1e-5f);
    w = Wv[r * 512 + c]; bb = bv[r]; mean = vme[r]; beta = vbe[r];
    post = 1.0f;
  }
  Wh[idx] = (unsigned short)f2h(w * sc * post);
  if (c == 0) bfv[o] = ((bb - mean) * sc + beta) * post;
}

// ---------------------------------------------------------------------------
// pos[h][n][d] = rel_h[h,d,hh] + rel_w[h,d,w], n = w*32+hh -> fp16.
// ---------------------------------------------------------------------------
__global__ __launch_bounds__(256) void pos_kernel(
    const float* __restrict__ rel_h, const float* __restrict__ rel_w,
    unsigned short* __restrict__ posH)
{
  int idx = blockIdx.x * 256 + threadIdx.x;  // [h][n][d] : 4*1024*32
  if (idx >= 4 * 1024 * 32) return;
  int h = idx >> 15, rem = idx & 32767, n = rem >> 5, d = rem & 31;
  int w = n >> 5, hh = n & 31;
  float v = rel_h[(h * 32 + d) * 32 + hh] + rel_w[(h * 32 + d) * 32 + w];
  posH[idx] = (unsigned short)f2h(v);
}

// ---------------------------------------------------------------------------
// Projection GEMM: per batch b, Y[768][1024] = Wh[768][512] * x_b[512][1024].
// Tile 128x128, BK=32, 16 k-steps, double-buffered, ONE barrier per step.
// A tile [128 rows][4 chunks of 8] swizzled (pos = c ^ sfn(row)), staged via
// gload_lds (pre-swizzled source). B tile same layout, staged via regs:
// issue f32 loads for step t+1 early, convert+ds_write after MFMAs (T14).
// LDS: 2x(8KB A) + 2x(8KB B) = 32KB -> 3 blocks/CU at grid 768.
// Epilogue (validated round 6): LDS transpose -> coalesced 16B stores.
// ---------------------------------------------------------------------------
__global__ __launch_bounds__(256) void proj_kernel(
    const float* __restrict__ x,
    const unsigned short* __restrict__ Wh, const float* __restrict__ bfv,
    unsigned short* __restrict__ qH, unsigned short* __restrict__ kH,
    unsigned short* __restrict__ vH)
{
  __shared__ __align__(16) short sm[16384];  // 32 KB: A dbuf @0, B dbuf @8192

  int bid = blockIdx.x;
  int b = bid / 48, rem = bid % 48, mblk = rem >> 3, nblk = rem & 7;
  int Mb = mblk * 128, Nb = nblk * 128;
  int t = threadIdx.x;
  int lane = t & 63, w4 = t >> 6, ln = lane & 15, g = lane >> 4;
  int wm = w4 >> 1, wn = w4 & 1;
  int kgp = t >> 5, lp = t & 31;
  int n0b = 2 * lp, hh = kgp & 1, cch = kgp >> 1;

  f32x4 acc[4][4];
  for (int i = 0; i < 4; i++)
    for (int j = 0; j < 4; j++) acc[i][j] = (f32x4){0.f, 0.f, 0.f, 0.f};

  float2 fB[8];

  // ---- staging helpers (LDS addressed via computed offsets, no ptr arrays)
  auto ISSUE_B = [&](int kb) {
    for (int e = 0; e < 2; e++)
      for (int rr = 0; rr < 4; rr++)
        fB[e * 4 + rr] = *(const float2*)&x[(b * 512 + kb + kgp * 4 + rr) * 1024 +
                                            Nb + n0b + e * 64];
  };
  auto ISSUE_A = [&](int kb, int bb) {
    for (int i = 0; i < 2; i++) {
      int grp = w4 + i * 4;
      int unit = grp * 64 + lane;
      int row = unit >> 2, pos = unit & 3;
      int j = pos ^ sfn(row);
      gload16(&Wh[(Mb + row) * 512 + kb + j * 8], &sm[bb * 4096 + grp * 512]);
    }
  };
  auto WRITE_B = [&](int bb) {
    short* Bt = &sm[8192 + bb * 4096];
    for (int e = 0; e < 2; e++) {
      int n0 = n0b + e * 64, n1 = n0 + 1;
      u32x2 w0 = (u32x2){pkh(fB[e * 4 + 0].x, fB[e * 4 + 1].x),
                         pkh(fB[e * 4 + 2].x, fB[e * 4 + 3].x)};
      u32x2 w1 = (u32x2){pkh(fB[e * 4 + 0].y, fB[e * 4 + 1].y),
                         pkh(fB[e * 4 + 2].y, fB[e * 4 + 3].y)};
      *(u32x2*)&Bt[n0 * 32 + (cch ^ sfn(n0)) * 8 + hh * 4] = w0;
      *(u32x2*)&Bt[n1 * 32 + (cch ^ sfn(n1)) * 8 + hh * 4] = w1;
    }
  };

  // ---- prologue: stage k-step 0 into buffer 0
  ISSUE_B(0);
  ISSUE_A(0, 0);
  WRITE_B(0);
  __syncthreads();

  // ---- main loop: 16 k-steps, one barrier each
  for (int ik = 0; ik < 16; ++ik) {
    int cur = ik & 1, nxt = cur ^ 1;
    if (ik < 15) {
      ISSUE_B((ik + 1) * 32);
      ISSUE_A((ik + 1) * 32, nxt);
    }
    const short* Ac = &sm[cur * 4096];
    const short* Bc = &sm[8192 + cur * 4096];
    f16x8 af[4], bf[4];
    for (int mt = 0; mt < 4; mt++) {
      int o = wm * 64 + mt * 16 + ln;
      af[mt] = *(const f16x8*)&Ac[o * 32 + (g ^ sfn(o)) * 8];
    }
    for (int nt = 0; nt < 4; nt++) {
      int n = wn * 64 + nt * 16 + ln;
      bf[nt] = *(const f16x8*)&Bc[n * 32 + (g ^ sfn(n)) * 8];
    }
    __builtin_amdgcn_s_setprio(1);
    for (int mt = 0; mt < 4; mt++)
      for (int nt = 0; nt < 4; nt++)
        acc[mt][nt] = MFMAH(af[mt], bf[nt], acc[mt][nt]);
    __builtin_amdgcn_s_setprio(0);
    __builtin_amdgcn_sched_barrier(0);
    if (ik < 15) WRITE_B(nxt);
    __syncthreads();
  }

  // ---- epilogue: two n-half passes (validated round 6)
  unsigned* smU = (unsigned*)sm;
  for (int p = 0; p < 2; p++) {
    if (p) __syncthreads();
    if (wn == p) {
      if (mblk < 2) {
        for (int mt = 0; mt < 4; mt++)
          for (int nt = 0; nt < 4; nt++) {
            float y0 = acc[mt][nt][0] + bfv[Mb + wm * 64 + mt * 16 + g * 4 + 0];
            float y1 = acc[mt][nt][1] + bfv[Mb + wm * 64 + mt * 16 + g * 4 + 1];
            float y2 = acc[mt][nt][2] + bfv[Mb + wm * 64 + mt * 16 + g * 4 + 2];
            float y3 = acc[mt][nt][3] + bfv[Mb + wm * 64 + mt * 16 + g * 4 + 3];
            u32x2 pk = (u32x2){pkh(y0, y1), pkh(y2, y3)};
            int nl = nt * 16 + ln;
            *(u32x2*)&smU[nl * 66 + wm * 32 + mt * 8 + g * 2] = pk;
          }
      } else {
        for (int mt = 0; mt < 4; mt++)
          for (int nt = 0; nt < 4; nt++)
            for (int r = 0; r < 4; r++) {
              int o = wm * 64 + mt * 16 + g * 4 + r;
              sm[o * 72 + nt * 16 + ln] = f2h(acc[mt][nt][r] + bfv[Mb + o]);
            }
      }
    }
    __syncthreads();
    if (mblk < 2) {
      unsigned short* dh = (mblk == 0) ? qH : kH;
      for (int it = 0; it < 4; it++) {
        int task = it * 256 + t;
        int h = task >> 8, nl = (task >> 2) & 63, qc = task & 3;
        u32x4 v4 = *(const u32x4*)&smU[nl * 66 + h * 16 + qc * 4];
        int gi = ((b * 4 + h) * 1024 + Nb + p * 64 + nl) * 32 + qc * 8;
        *(u32x4*)&dh[gi] = v4;
      }
    } else {
      int bh = b * 4 + (mblk - 2);
      for (int it = 0; it < 4; it++) {
        int task = it * 256 + t;
        int o = task >> 3, qc = task & 7;
        u32x4 vv = *(const u32x4*)&sm[o * 72 + qc * 8];
        *(u32x4*)&vH[(bh * 128 + o) * 1024 + Nb + p * 64 + qc * 8] = vv;
      }
    }
  }
}

// ---------------------------------------------------------------------------
// Flash attention (unchanged from round 8 — validated).
// ---------------------------------------------------------------------------
__global__ __launch_bounds__(512, 4) void attn_kernel(
    const float* __restrict__ x,
    const unsigned short* __restrict__ qH, const unsigned short* __restrict__ kH,
    const unsigned short* __restrict__ posH, const unsigned short* __restrict__ vH,
    float* __restrict__ out)
{
  __shared__ __align__(16) short sm[2 * 12288 + 8 * 1152];  // 67584 B

  int bid = blockIdx.x;
  int bh = (bid & 7) * 8 + ((bid >> 3) & 7);
  int qt = bid >> 6;
  int b = bh >> 2, h = bh & 3;
  int t = threadIdx.x;
  int lane = t & 63, w = t >> 6, ln = lane & 15, g = (lane >> 4) & 3;

  int qrow = qt * 128 + w * 16 + ln;
  f16x8 bQ   = *(const f16x8*)&qH[(bh * 1024 + qrow) * 32 + g * 8];
  f16x8 bPos = *(const f16x8*)&posH[(h * 1024 + qrow) * 32 + g * 8];

  f16x8 aOnes;
  {
    _Float16 o1 = (ln == 0) ? (_Float16)1.0f : (_Float16)0.0f;
    for (int i = 0; i < 8; i++) aOnes[i] = o1;
  }

  f32x4 acc[9];  // [0..7] = output channels, [8] = l row-sum (m=0 row)
  for (int ct = 0; ct < 9; ct++) acc[ct] = (f32x4){0.f, 0.f, 0.f, 0.f};
  float m_run = -1e30f;

  short* Pw = &sm[24576 + w * 1152];

  auto STAGE = [&](int bb, int jb) {
    {
      int u = t & 255;
      int r = u >> 2;
      int ch = (u & 3) ^ (r & 3) ^ ((r >> 2) & 3);
      long gq = (long)(bh * 1024 + jb + r) * 32 + ch * 8;
      const unsigned short* src = (t < 256) ? kH : qH;
      short* base = &sm[bb * 12288 + ((t < 256) ? 0 : 2048) + (w & 3) * 512];
      gload16(&src[gq], base);
    }
    for (int i = 0; i < 2; i++) {
      int u = t + i * 512;
      int c = u >> 3;
      int vch = (u & 7) ^ (c & 7);
      long gv = (long)(bh * 128 + c) * 1024 + jb + vch * 8;
      short* base = &sm[bb * 12288 + 4096 + (w + i * 8) * 512];
      gload16(&vH[gv], base);
    }
  };

  STAGE(0, 0);

  for (int it = 0; it < 16; ++it) {
    int cur = it & 1;
    if (it < 15) {
      STAGE(cur ^ 1, (it + 1) * 64);
      asm volatile("s_waitcnt vmcnt(3)" ::: "memory");
    } else {
      asm volatile("s_waitcnt vmcnt(0)" ::: "memory");
    }
    __builtin_amdgcn_s_barrier();
    __builtin_amdgcn_sched_barrier(0);

    const short* B = &sm[cur * 12288];

    f16x8 aK[4], aQ[4];
    for (int kt = 0; kt < 4; kt++) {
      int r = kt * 16 + ln;
      int p = g ^ (r & 3) ^ ((r >> 2) & 3);
      int off = r * 32 + p * 8;
      aK[kt] = *(const f16x8*)&B[off];
      aQ[kt] = *(const f16x8*)&B[2048 + off];
    }

    f32x4 s[4];
    for (int kt = 0; kt < 4; kt++) s[kt] = (f32x4){0.f, 0.f, 0.f, 0.f};
    __builtin_amdgcn_s_setprio(1);
    for (int kt = 0; kt < 4; kt++) s[kt] = MFMAH(aK[kt], bQ, s[kt]);
    for (int kt = 0; kt < 4; kt++) s[kt] = MFMAH(aQ[kt], bPos, s[kt]);
    __builtin_amdgcn_s_setprio(0);

    float m0 = fmaxf(fmaxf(s[0][0], s[0][1]), fmaxf(s[0][2], s[0][3]));
    float m1 = fmaxf(fmaxf(s[1][0], s[1][1]), fmaxf(s[1][2], s[1][3]));
    float m2 = fmaxf(fmaxf(s[2][0], s[2][1]), fmaxf(s[2][2], s[2][3]));
    float m3 = fmaxf(fmaxf(s[3][0], s[3][1]), fmaxf(s[3][2], s[3][3]));
    float mx = fmaxf(fmaxf(m0, m1), fmaxf(m2, m3));
    if (__any(mx > m_run + 8.f)) {
      float mxf = fmaxf(mx, __shfl_xor(mx, 16));
      mxf = fmaxf(mxf, __shfl_xor(mxf, 32));
      float mnew = fmaxf(m_run, mxf);
      float scl = __builtin_amdgcn_exp2f(m_run - mnew);
      for (int ct = 0; ct < 9; ct++) acc[ct] *= scl;
      m_run = mnew;
    }
    for (int kt = 0; kt < 4; kt++)
      for (int r = 0; r < 4; r++)
        s[kt][r] = __builtin_amdgcn_exp2f(s[kt][r] - m_run);

    for (int kt = 0; kt < 4; kt++) {
      u32x2 pk = (u32x2){pkh(s[kt][0], s[kt][1]), pkh(s[kt][2], s[kt][3])};
      *(u32x2*)&Pw[ln * 72 + kt * 16 + g * 4] = pk;
    }
    asm volatile("s_waitcnt lgkmcnt(0)" ::: "memory");
    __builtin_amdgcn_sched_barrier(0);
    f16x8 pFrag[2];
    for (int st2 = 0; st2 < 2; st2++)
      pFrag[st2] = *(const f16x8*)&Pw[ln * 72 + st2 * 32 + g * 8];

    __builtin_amdgcn_s_setprio(1);
    for (int ct = 0; ct < 8; ct++)
      for (int st2 = 0; st2 < 2; st2++) {
        int c = ct * 16 + ln;
        int pos = (st2 * 4 + g) ^ (c & 7);
        f16x8 av = *(const f16x8*)&B[4096 + c * 64 + pos * 8];
        acc[ct] = MFMAH(av, pFrag[st2], acc[ct]);
      }
    acc[8] = MFMAH(aOnes, pFrag[0], acc[8]);
    acc[8] = MFMAH(aOnes, pFrag[1], acc[8]);
    __builtin_amdgcn_s_setprio(0);

    __builtin_amdgcn_sched_barrier(0);
    __builtin_amdgcn_s_barrier();
    __builtin_amdgcn_sched_barrier(0);
  }

  float lsum = __shfl(acc[8][0], ln);
  float inv = 1.0f / lsum;
  int m = qt * 128 + w * 16 + ln;
  for (int ct = 0; ct < 8; ct++)
    for (int r = 0; r < 4; r++) {
      int c = h * 128 + ct * 16 + g * 4 + r;
      int gi = (b * 512 + c) * 1024 + m;
      out[gi] = acc[ct][r] * inv + x[gi];
    }
}

// ---------------------------------------------------------------------------
extern "C" void kernel_launch(void* const* d_in, const int* in_sizes, int n_in,
                              void* d_out, int out_size, void* d_ws, size_t ws_size,
                              hipStream_t stream) {
  const float* x    = (const float*)d_in[0];
  const float* Wq   = (const float*)d_in[1];
  const float* bq   = (const float*)d_in[2];
  const float* qg   = (const float*)d_in[3];
  const float* qbe  = (const float*)d_in[4];
  const float* qme  = (const float*)d_in[5];
  const float* qva  = (const float*)d_in[6];
  const float* Wk   = (const float*)d_in[7];
  const float* bk   = (const float*)d_in[8];
  const float* kg   = (const float*)d_in[9];
  const float* kbe  = (const float*)d_in[10];
  const float* kme  = (const float*)d_in[11];
  const float* kva  = (const float*)d_in[12];
  const float* Wv   = (const float*)d_in[13];
  const float* bv   = (const float*)d_in[14];
  const float* vg   = (const float*)d_in[15];
  const float* vbe  = (const float*)d_in[16];
  const float* vme  = (const float*)d_in[17];
  const float* vva  = (const float*)d_in[18];
  const float* relh = (const float*)d_in[19];
  const float* relw = (const float*)d_in[20];
  float* outp = (float*)d_out;

  unsigned char* ws = (unsigned char*)d_ws;
  unsigned short* Whp  = (unsigned short*)(ws + 0);        // 768*512*2
  float*          bfv  = (float*)(ws + 786432);            // 768*4
  unsigned short* qHp  = (unsigned short*)(ws + 789504);   // 64*1024*32*2
  unsigned short* kHp  = (unsigned short*)(ws + 4983808);
  unsigned short* posHp= (unsigned short*)(ws + 9178112);  // 4*1024*32*2
  unsigned short* vHp  = (unsigned short*)(ws + 9440256);  // 64*128*1024*2
  // total ws used: 26,217,472 bytes

  fold_kernel<<<1536, 256, 0, stream>>>(Wq, bq, qg, qbe, qme, qva,
                                        Wk, bk, kg, kbe, kme, kva,
                                        Wv, bv, vg, vbe, vme, vva,
                                        Whp, bfv);
  pos_kernel<<<512, 256, 0, stream>>>(relh, relw, posHp);
  proj_kernel<<<768, 256, 0, stream>>>(x, Whp, bfv, qHp, kHp, vHp);
  attn_kernel<<<512, 512, 0, stream>>>(x, qHp, kHp, posHp, vHp, outp);
}

// Round 11
// 84.365 us; speedup vs baseline: 1.0407x; 1.0407x over previous
//
#include <hip/hip_runtime.h>

// ---------------------------------------------------------------------------
// MHSA fused block, MI355X (gfx950).
// fold(BN->W, fp16, q-rows pre-scaled by log2e) -> pos table (fp16) ->
// QKV projection GEMM (fp16 MFMA, 512-thread 128x256 tile, BK=64,
// r8-proven swizzle/epilogue) -> flash attention (8-wave blocks, exp2
// softmax, l-sum via ones-MFMA, dbuf gload_lds pipeline, XCD-local L2).
// ---------------------------------------------------------------------------

typedef _Float16 f16x8 __attribute__((ext_vector_type(8)));
typedef __attribute__((ext_vector_type(4))) float f32x4;
typedef __attribute__((ext_vector_type(4))) unsigned int u32x4;
typedef __attribute__((ext_vector_type(2))) unsigned int u32x2;

#define MFMAH(a, b, c) __builtin_amdgcn_mfma_f32_16x16x32_f16(a, b, c, 0, 0, 0)
#define LOG2E 1.4426950408889634f

__device__ __forceinline__ unsigned pkh(float a, float b) {
  auto p = __builtin_amdgcn_cvt_pkrtz(a, b);  // __fp16 ext_vector(2)
  return __builtin_bit_cast(unsigned, p);
}
__device__ __forceinline__ short f2h(float a) {
  _Float16 h = (_Float16)a;
  return __builtin_bit_cast(short, h);
}

// 16B global -> LDS direct (wave-uniform LDS base + lane*16)
__device__ __forceinline__ void gload16(const void* g, void* l) {
  __builtin_amdgcn_global_load_lds(
      (const __attribute__((address_space(1))) void*)g,
      (__attribute__((address_space(3))) void*)l, 16, 0, 0);
}

// ---------------------------------------------------------------------------
// Fold BN into conv weights -> fp16. Wh[768][512] (rows: 128 q, 128 k, 512 v).
// ---------------------------------------------------------------------------
__global__ __launch_bounds__(256) void fold_kernel(
    const float* __restrict__ Wq, const float* __restrict__ bq,
    const float* __restrict__ qg, const float* __restrict__ qbe,
    const float* __restrict__ qme, const float* __restrict__ qva,
    const float* __restrict__ Wk, const float* __restrict__ bk,
    const float* __restrict__ kg, const float* __restrict__ kbe,
    const float* __restrict__ kme, const float* __restrict__ kva,
    const float* __restrict__ Wv, const float* __restrict__ bv,
    const float* __restrict__ vg, const float* __restrict__ vbe,
    const float* __restrict__ vme, const float* __restrict__ vva,
    unsigned short* __restrict__ Wh, float* __restrict__ bfv)
{
  int idx = blockIdx.x * 256 + threadIdx.x;
  if (idx >= 768 * 512) return;
  int o = idx >> 9, c = idx & 511;
  float w, sc, bb, mean, beta, post;
  if (o < 128) {
    sc = qg[o] / sqrtf(qva[o] + 1e-5f);
    w = Wq[o * 512 + c]; bb = bq[o]; mean = qme[o]; beta = qbe[o];
    post = LOG2E;
  } else if (o < 256) {
    int r = o - 128;
    sc = kg[r] / sqrtf(kva[r] + 1e-5f);
    w = Wk[r * 512 + c]; bb = bk[r]; mean = kme[r]; beta = kbe[r];
    post = 1.0f;
  } else {
    int r = o - 256;
    sc = vg[r] / sqrtf(vva[r] + 1e-5f);
    w = Wv[r * 512 + c]; bb = bv[r]; mean = vme[r]; beta = vbe[r];
    post = 1.0f;
  }
  Wh[idx] = (unsigned short)f2h(w * sc * post);
  if (c == 0) bfv[o] = ((bb - mean) * sc + beta) * post;
}

// ---------------------------------------------------------------------------
__global__ __launch_bounds__(256) void pos_kernel(
    const float* __restrict__ rel_h, const float* __restrict__ rel_w,
    unsigned short* __restrict__ posH)
{
  int idx = blockIdx.x * 256 + threadIdx.x;  // [h][n][d] : 4*1024*32
  if (idx >= 4 * 1024 * 32) return;
  int h = idx >> 15, rem = idx & 32767, n = rem >> 5, d = rem & 31;
  int w = n >> 5, hh = n & 31;
  float v = rel_h[(h * 32 + d) * 32 + hh] + rel_w[(h * 32 + d) * 32 + w];
  posH[idx] = (unsigned short)f2h(v);
}

// ---------------------------------------------------------------------------
// Projection GEMM: Y[768][1024] = Wh[768][512] * x_b[512][1024] per batch.
// 512 threads / 8 waves (wave tile 64x64), block tile 128M x 256N, BK=64,
// 8 k-steps, single-buffered 2-barrier loop (r8 structure, bigger block for
// occupancy: waves/CU scale with block size per r7/r10 occupancy evidence).
// LDS 48KB: A[128][64] fp16 @0 (8-slot swizzle), B[256][64] @8192.
// A staged via gload_lds (pre-swizzled source); B via 16 coalesced float2 +
// 4 ds_write_b128 (slot = k8 ^ (n&7); lane-parity swap covers 8 slots/instr).
// Epilogue: r8-validated LDS transpose, 4 n-passes of 64.
// ---------------------------------------------------------------------------
__global__ __launch_bounds__(512) void proj_kernel(
    const float* __restrict__ x,
    const unsigned short* __restrict__ Wh, const float* __restrict__ bfv,
    unsigned short* __restrict__ qH, unsigned short* __restrict__ kH,
    unsigned short* __restrict__ vH)
{
  __shared__ __align__(16) short sm[24576];  // 48 KB: A @0, B @8192

  int bid = blockIdx.x;
  int b = bid / 24, rem = bid % 24, mblk = rem >> 2, nblk = rem & 3;
  int Mb = mblk * 128, Nb = nblk * 256;
  int t = threadIdx.x;
  int lane = t & 63, w = t >> 6, ln = lane & 15, g = (lane >> 4) & 3;
  int wm = w >> 2, wn = w & 3;            // wave tile: 64 rows x 64 cols
  int kg = t >> 7, np = t & 127;          // B staging: 16 k-rows x 2 n-cols
  int n0 = 2 * np;
  int swp = (np >> 2) & 1;

  f32x4 acc[4][4];
  for (int i = 0; i < 4; i++)
    for (int j = 0; j < 4; j++) acc[i][j] = (f32x4){0.f, 0.f, 0.f, 0.f};

  for (int kb = 0; kb < 512; kb += 64) {
    __syncthreads();
    // ---- stage A via gload_lds: 1024 units (row,pos), 2 per thread
    for (int i = 0; i < 2; i++) {
      int grp = w + i * 8;
      int unit = grp * 64 + lane;
      int row = unit >> 3, pos = unit & 7;
      int j = pos ^ (row & 7);
      gload16(&Wh[(Mb + row) * 512 + kb + j * 8], &sm[grp * 512]);
    }
    // ---- stage B: 16 float2 (16 k-rows x 2 n), pack, 4 b128 swizzled writes
    {
      float2 fB[16];
      for (int rr = 0; rr < 16; rr++)
        fB[rr] = *(const float2*)&x[(b * 512 + kb + kg * 16 + rr) * 1024 +
                                    Nb + n0];
      short* Bt = sm + 8192;
      for (int s = 0; s < 2; s++) {
        u32x4 wE = (u32x4){pkh(fB[s * 8 + 0].x, fB[s * 8 + 1].x),
                           pkh(fB[s * 8 + 2].x, fB[s * 8 + 3].x),
                           pkh(fB[s * 8 + 4].x, fB[s * 8 + 5].x),
                           pkh(fB[s * 8 + 6].x, fB[s * 8 + 7].x)};
        u32x4 wO = (u32x4){pkh(fB[s * 8 + 0].y, fB[s * 8 + 1].y),
                           pkh(fB[s * 8 + 2].y, fB[s * 8 + 3].y),
                           pkh(fB[s * 8 + 4].y, fB[s * 8 + 5].y),
                           pkh(fB[s * 8 + 6].y, fB[s * 8 + 7].y)};
        int k8 = kg * 2 + s;
        int offE = n0 * 64 + 8 * (k8 ^ (n0 & 7));
        int offO = (n0 + 1) * 64 + 8 * (k8 ^ ((n0 + 1) & 7));
        // parity swap: each instruction's lanes cover all 8 slots (32 banks)
        int o1 = swp ? offO : offE, o2 = swp ? offE : offO;
        u32x4 d1 = swp ? wO : wE, d2 = swp ? wE : wO;
        *(u32x4*)&Bt[o1] = d1;
        *(u32x4*)&Bt[o2] = d2;
      }
    }
    __syncthreads();

    // ---- fragments + MFMA (per-wave identical to validated r8)
    const short* Bt = sm + 8192;
    for (int ks = 0; ks < 2; ks++) {
      f16x8 af[4], bf[4];
      for (int mt = 0; mt < 4; mt++) {
        int o = wm * 64 + mt * 16 + ln;
        af[mt] = *(const f16x8*)&sm[o * 64 + 8 * ((ks * 4 + g) ^ (o & 7))];
      }
      for (int nt = 0; nt < 4; nt++) {
        int n = wn * 64 + nt * 16 + ln;
        bf[nt] = *(const f16x8*)&Bt[n * 64 + 8 * ((ks * 4 + g) ^ (n & 7))];
      }
      __builtin_amdgcn_s_setprio(1);
      for (int mt = 0; mt < 4; mt++)
        for (int nt = 0; nt < 4; nt++)
          acc[mt][nt] = MFMAH(af[mt], bf[nt], acc[mt][nt]);
      __builtin_amdgcn_s_setprio(0);
    }
  }

  // ---- epilogue: 4 n-passes of 64 (pass p: waves with wn==p write LDS)
  unsigned* smU = (unsigned*)sm;
  for (int p = 0; p < 4; p++) {
    __syncthreads();
    if (wn == p) {
      if (mblk < 2) {
        // q/k: LDS [nl][o/2] u32 (2 fp16), stride 66 u32, b64 writes
        for (int mt = 0; mt < 4; mt++)
          for (int nt = 0; nt < 4; nt++) {
            float y0 = acc[mt][nt][0] + bfv[Mb + wm * 64 + mt * 16 + g * 4 + 0];
            float y1 = acc[mt][nt][1] + bfv[Mb + wm * 64 + mt * 16 + g * 4 + 1];
            float y2 = acc[mt][nt][2] + bfv[Mb + wm * 64 + mt * 16 + g * 4 + 2];
            float y3 = acc[mt][nt][3] + bfv[Mb + wm * 64 + mt * 16 + g * 4 + 3];
            u32x2 pk = (u32x2){pkh(y0, y1), pkh(y2, y3)};
            int nl = nt * 16 + ln;
            *(u32x2*)&smU[nl * 66 + wm * 32 + mt * 8 + g * 2] = pk;
          }
      } else {
        // v: LDS [o][nl] fp16, stride 72 shorts
        for (int mt = 0; mt < 4; mt++)
          for (int nt = 0; nt < 4; nt++)
            for (int r = 0; r < 4; r++) {
              int o = wm * 64 + mt * 16 + g * 4 + r;
              sm[o * 72 + nt * 16 + ln] = f2h(acc[mt][nt][r] + bfv[Mb + o]);
            }
      }
    }
    __syncthreads();
    if (mblk < 2) {
      unsigned short* dh = (mblk == 0) ? qH : kH;
      for (int it = 0; it < 2; it++) {
        int task = it * 512 + t;
        int h = task >> 8, nl = (task >> 2) & 63, qc = task & 3;
        u32x4 v4 = *(const u32x4*)&smU[nl * 66 + h * 16 + qc * 4];
        int gi = ((b * 4 + h) * 1024 + Nb + p * 64 + nl) * 32 + qc * 8;
        *(u32x4*)&dh[gi] = v4;
      }
    } else {
      int bh = b * 4 + (mblk - 2);
      for (int it = 0; it < 2; it++) {
        int task = it * 512 + t;
        int o = task >> 3, qc = task & 7;
        u32x4 vv = *(const u32x4*)&sm[o * 72 + qc * 8];
        *(u32x4*)&vH[(bh * 128 + o) * 1024 + Nb + p * 64 + qc * 8] = vv;
      }
    }
  }
}

// ---------------------------------------------------------------------------
// Flash attention (unchanged from round 8/10 — validated).
// ---------------------------------------------------------------------------
__global__ __launch_bounds__(512, 4) void attn_kernel(
    const float* __restrict__ x,
    const unsigned short* __restrict__ qH, const unsigned short* __restrict__ kH,
    const unsigned short* __restrict__ posH, const unsigned short* __restrict__ vH,
    float* __restrict__ out)
{
  __shared__ __align__(16) short sm[2 * 12288 + 8 * 1152];  // 67584 B

  int bid = blockIdx.x;
  int bh = (bid & 7) * 8 + ((bid >> 3) & 7);
  int qt = bid >> 6;
  int b = bh >> 2, h = bh & 3;
  int t = threadIdx.x;
  int lane = t & 63, w = t >> 6, ln = lane & 15, g = (lane >> 4) & 3;

  int qrow = qt * 128 + w * 16 + ln;
  f16x8 bQ   = *(const f16x8*)&qH[(bh * 1024 + qrow) * 32 + g * 8];
  f16x8 bPos = *(const f16x8*)&posH[(h * 1024 + qrow) * 32 + g * 8];

  f16x8 aOnes;
  {
    _Float16 o1 = (ln == 0) ? (_Float16)1.0f : (_Float16)0.0f;
    for (int i = 0; i < 8; i++) aOnes[i] = o1;
  }

  f32x4 acc[9];  // [0..7] = output channels, [8] = l row-sum (m=0 row)
  for (int ct = 0; ct < 9; ct++) acc[ct] = (f32x4){0.f, 0.f, 0.f, 0.f};
  float m_run = -1e30f;

  short* Pw = &sm[24576 + w * 1152];

  auto STAGE = [&](int bb, int jb) {
    {
      int u = t & 255;
      int r = u >> 2;
      int ch = (u & 3) ^ (r & 3) ^ ((r >> 2) & 3);
      long gq = (long)(bh * 1024 + jb + r) * 32 + ch * 8;
      const unsigned short* src = (t < 256) ? kH : qH;
      short* base = &sm[bb * 12288 + ((t < 256) ? 0 : 2048) + (w & 3) * 512];
      gload16(&src[gq], base);
    }
    for (int i = 0; i < 2; i++) {
      int u = t + i * 512;
      int c = u >> 3;
      int vch = (u & 7) ^ (c & 7);
      long gv = (long)(bh * 128 + c) * 1024 + jb + vch * 8;
      short* base = &sm[bb * 12288 + 4096 + (w + i * 8) * 512];
      gload16(&vH[gv], base);
    }
  };

  STAGE(0, 0);

  for (int it = 0; it < 16; ++it) {
    int cur = it & 1;
    if (it < 15) {
      STAGE(cur ^ 1, (it + 1) * 64);
      asm volatile("s_waitcnt vmcnt(3)" ::: "memory");
    } else {
      asm volatile("s_waitcnt vmcnt(0)" ::: "memory");
    }
    __builtin_amdgcn_s_barrier();
    __builtin_amdgcn_sched_barrier(0);

    const short* B = &sm[cur * 12288];

    f16x8 aK[4], aQ[4];
    for (int kt = 0; kt < 4; kt++) {
      int r = kt * 16 + ln;
      int p = g ^ (r & 3) ^ ((r >> 2) & 3);
      int off = r * 32 + p * 8;
      aK[kt] = *(const f16x8*)&B[off];
      aQ[kt] = *(const f16x8*)&B[2048 + off];
    }

    f32x4 s[4];
    for (int kt = 0; kt < 4; kt++) s[kt] = (f32x4){0.f, 0.f, 0.f, 0.f};
    __builtin_amdgcn_s_setprio(1);
    for (int kt = 0; kt < 4; kt++) s[kt] = MFMAH(aK[kt], bQ, s[kt]);
    for (int kt = 0; kt < 4; kt++) s[kt] = MFMAH(aQ[kt], bPos, s[kt]);
    __builtin_amdgcn_s_setprio(0);

    float m0 = fmaxf(fmaxf(s[0][0], s[0][1]), fmaxf(s[0][2], s[0][3]));
    float m1 = fmaxf(fmaxf(s[1][0], s[1][1]), fmaxf(s[1][2], s[1][3]));
    float m2 = fmaxf(fmaxf(s[2][0], s[2][1]), fmaxf(s[2][2], s[2][3]));
    float m3 = fmaxf(fmaxf(s[3][0], s[3][1]), fmaxf(s[3][2], s[3][3]));
    float mx = fmaxf(fmaxf(m0, m1), fmaxf(m2, m3));
    if (__any(mx > m_run + 8.f)) {
      float mxf = fmaxf(mx, __shfl_xor(mx, 16));
      mxf = fmaxf(mxf, __shfl_xor(mxf, 32));
      float mnew = fmaxf(m_run, mxf);
      float scl = __builtin_amdgcn_exp2f(m_run - mnew);
      for (int ct = 0; ct < 9; ct++) acc[ct] *= scl;
      m_run = mnew;
    }
    for (int kt = 0; kt < 4; kt++)
      for (int r = 0; r < 4; r++)
        s[kt][r] = __builtin_amdgcn_exp2f(s[kt][r] - m_run);

    for (int kt = 0; kt < 4; kt++) {
      u32x2 pk = (u32x2){pkh(s[kt][0], s[kt][1]), pkh(s[kt][2], s[kt][3])};
      *(u32x2*)&Pw[ln * 72 + kt * 16 + g * 4] = pk;
    }
    asm volatile("s_waitcnt lgkmcnt(0)" ::: "memory");
    __builtin_amdgcn_sched_barrier(0);
    f16x8 pFrag[2];
    for (int st2 = 0; st2 < 2; st2++)
      pFrag[st2] = *(const f16x8*)&Pw[ln * 72 + st2 * 32 + g * 8];

    __builtin_amdgcn_s_setprio(1);
    for (int ct = 0; ct < 8; ct++)
      for (int st2 = 0; st2 < 2; st2++) {
        int c = ct * 16 + ln;
        int pos = (st2 * 4 + g) ^ (c & 7);
        f16x8 av = *(const f16x8*)&B[4096 + c * 64 + pos * 8];
        acc[ct] = MFMAH(av, pFrag[st2], acc[ct]);
      }
    acc[8] = MFMAH(aOnes, pFrag[0], acc[8]);
    acc[8] = MFMAH(aOnes, pFrag[1], acc[8]);
    __builtin_amdgcn_s_setprio(0);

    __builtin_amdgcn_sched_barrier(0);
    __builtin_amdgcn_s_barrier();
    __builtin_amdgcn_sched_barrier(0);
  }

  float lsum = __shfl(acc[8][0], ln);
  float inv = 1.0f / lsum;
  int m = qt * 128 + w * 16 + ln;
  for (int ct = 0; ct < 8; ct++)
    for (int r = 0; r < 4; r++) {
      int c = h * 128 + ct * 16 + g * 4 + r;
      int gi = (b * 512 + c) * 1024 + m;
      out[gi] = acc[ct][r] * inv + x[gi];
    }
}

// ---------------------------------------------------------------------------
extern "C" void kernel_launch(void* const* d_in, const int* in_sizes, int n_in,
                              void* d_out, int out_size, void* d_ws, size_t ws_size,
                              hipStream_t stream) {
  const float* x    = (const float*)d_in[0];
  const float* Wq   = (const float*)d_in[1];
  const float* bq   = (const float*)d_in[2];
  const float* qg   = (const float*)d_in[3];
  const float* qbe  = (const float*)d_in[4];
  const float* qme  = (const float*)d_in[5];
  const float* qva  = (const float*)d_in[6];
  const float* Wk   = (const float*)d_in[7];
  const float* bk   = (const float*)d_in[8];
  const float* kg   = (const float*)d_in[9];
  const float* kbe  = (const float*)d_in[10];
  const float* kme  = (const float*)d_in[11];
  const float* kva  = (const float*)d_in[12];
  const float* Wv   = (const float*)d_in[13];
  const float* bv   = (const float*)d_in[14];
  const float* vg   = (const float*)d_in[15];
  const float* vbe  = (const float*)d_in[16];
  const float* vme  = (const float*)d_in[17];
  const float* vva  = (const float*)d_in[18];
  const float* relh = (const float*)d_in[19];
  const float* relw = (const float*)d_in[20];
  float* outp = (float*)d_out;

  unsigned char* ws = (unsigned char*)d_ws;
  unsigned short* Whp  = (unsigned short*)(ws + 0);        // 768*512*2
  float*          bfv  = (float*)(ws + 786432);            // 768*4
  unsigned short* qHp  = (unsigned short*)(ws + 789504);   // 64*1024*32*2
  unsigned short* kHp  = (unsigned short*)(ws + 4983808);
  unsigned short* posHp= (unsigned short*)(ws + 9178112);  // 4*1024*32*2
  unsigned short* vHp  = (unsigned short*)(ws + 9440256);  // 64*128*1024*2
  // total ws used: 26,217,472 bytes

  fold_kernel<<<1536, 256, 0, stream>>>(Wq, bq, qg, qbe, qme, qva,
                                        Wk, bk, kg, kbe, kme, kva,
                                        Wv, bv, vg, vbe, vme, vva,
                                        Whp, bfv);
  pos_kernel<<<512, 256, 0, stream>>>(relh, relw, posHp);
  proj_kernel<<<384, 512, 0, stream>>>(x, Whp, bfv, qHp, kHp, vHp);
  attn_kernel<<<512, 512, 0, stream>>>(x, qHp, kHp, posHp, vHp, outp);
}

// Round 12
// 76.134 us; speedup vs baseline: 1.1533x; 1.1081x over previous
//
#include <hip/hip_runtime.h>

// ---------------------------------------------------------------------------
// MHSA fused block, MI355X (gfx950).
// setup(fold BN->W fp16 + pos table) -> QKV projection GEMM (fp16 MFMA,
// 512-thread 128x128 tile, grid 768 = 3 blocks/CU) -> flash attention
// (8-wave blocks, exp2 softmax, l-sum via ones-MFMA, dbuf gload_lds
// pipeline, XCD-local L2 reuse).
// ---------------------------------------------------------------------------

typedef _Float16 f16x8 __attribute__((ext_vector_type(8)));
typedef __attribute__((ext_vector_type(4))) float f32x4;
typedef __attribute__((ext_vector_type(4))) unsigned int u32x4;
typedef __attribute__((ext_vector_type(2))) unsigned int u32x2;

#define MFMAH(a, b, c) __builtin_amdgcn_mfma_f32_16x16x32_f16(a, b, c, 0, 0, 0)
#define LOG2E 1.4426950408889634f

__device__ __forceinline__ unsigned pkh(float a, float b) {
  auto p = __builtin_amdgcn_cvt_pkrtz(a, b);  // __fp16 ext_vector(2)
  return __builtin_bit_cast(unsigned, p);
}
__device__ __forceinline__ short f2h(float a) {
  _Float16 h = (_Float16)a;
  return __builtin_bit_cast(short, h);
}

// 16B global -> LDS direct (wave-uniform LDS base + lane*16)
__device__ __forceinline__ void gload16(const void* g, void* l) {
  __builtin_amdgcn_global_load_lds(
      (const __attribute__((address_space(1))) void*)g,
      (__attribute__((address_space(3))) void*)l, 16, 0, 0);
}

// ---------------------------------------------------------------------------
// setup: blocks [0,1536) fold BN into Wh fp16 (q rows pre-scaled by log2e);
//        blocks [1536,2048) build pos table fp16.
// ---------------------------------------------------------------------------
__global__ __launch_bounds__(256) void setup_kernel(
    const float* __restrict__ Wq, const float* __restrict__ bq,
    const float* __restrict__ qg, const float* __restrict__ qbe,
    const float* __restrict__ qme, const float* __restrict__ qva,
    const float* __restrict__ Wk, const float* __restrict__ bk,
    const float* __restrict__ kg, const float* __restrict__ kbe,
    const float* __restrict__ kme, const float* __restrict__ kva,
    const float* __restrict__ Wv, const float* __restrict__ bv,
    const float* __restrict__ vg, const float* __restrict__ vbe,
    const float* __restrict__ vme, const float* __restrict__ vva,
    const float* __restrict__ rel_h, const float* __restrict__ rel_w,
    unsigned short* __restrict__ Wh, float* __restrict__ bfv,
    unsigned short* __restrict__ posH)
{
  int bid = blockIdx.x;
  if (bid < 1536) {
    int idx = bid * 256 + threadIdx.x;
    if (idx >= 768 * 512) return;
    int o = idx >> 9, c = idx & 511;
    float w, sc, bb, mean, beta, post;
    if (o < 128) {
      sc = qg[o] / sqrtf(qva[o] + 1e-5f);
      w = Wq[o * 512 + c]; bb = bq[o]; mean = qme[o]; beta = qbe[o];
      post = LOG2E;
    } else if (o < 256) {
      int r = o - 128;
      sc = kg[r] / sqrtf(kva[r] + 1e-5f);
      w = Wk[r * 512 + c]; bb = bk[r]; mean = kme[r]; beta = kbe[r];
      post = 1.0f;
    } else {
      int r = o - 256;
      sc = vg[r] / sqrtf(vva[r] + 1e-5f);
      w = Wv[r * 512 + c]; bb = bv[r]; mean = vme[r]; beta = vbe[r];
      post = 1.0f;
    }
    Wh[idx] = (unsigned short)f2h(w * sc * post);
    if (c == 0) bfv[o] = ((bb - mean) * sc + beta) * post;
  } else {
    int idx = (bid - 1536) * 256 + threadIdx.x;  // [h][n][d] : 4*1024*32
    if (idx >= 4 * 1024 * 32) return;
    int h = idx >> 15, rem = idx & 32767, n = rem >> 5, d = rem & 31;
    int w = n >> 5, hh = n & 31;
    float v = rel_h[(h * 32 + d) * 32 + hh] + rel_w[(h * 32 + d) * 32 + w];
    posH[idx] = (unsigned short)f2h(v);
  }
}

// ---------------------------------------------------------------------------
// Projection GEMM: Y[768][1024] = Wh[768][512] * x_b[512][1024] per batch.
// 512 threads / 8 waves (2m x 4n, wave tile 64x32), block tile 128x128,
// BK=64, 8 k-steps. Grid 768 -> 3 blocks/CU (LDS 32KB), 24 waves/CU.
// A via gload_lds (pre-swizzled source, r11 formula); B via 8 coalesced
// float2 + 2 parity-swapped b128 swizzled writes (r11 formula, kg=t>>6).
// Epilogue: r11-validated LDS transpose, 2 n-passes of 64.
// ---------------------------------------------------------------------------
__global__ __launch_bounds__(512) void proj_kernel(
    const float* __restrict__ x,
    const unsigned short* __restrict__ Wh, const float* __restrict__ bfv,
    unsigned short* __restrict__ qH, unsigned short* __restrict__ kH,
    unsigned short* __restrict__ vH)
{
  __shared__ __align__(16) short sm[16384];  // 32 KB: A @0, B @8192

  int bid = blockIdx.x;
  int b = bid / 48, rem = bid % 48, mblk = rem >> 3, nblk = rem & 7;
  int Mb = mblk * 128, Nb = nblk * 128;
  int t = threadIdx.x;
  int lane = t & 63, w = t >> 6, ln = lane & 15, g = (lane >> 4) & 3;
  int wm = w >> 2, wn = w & 3;            // wave tile: 64 rows x 32 cols
  int kg8 = t >> 6, np = t & 63;          // B staging: 8 k-rows x 1 n-pair
  int n0 = 2 * np;
  int swp = (np >> 2) & 1;

  f32x4 acc[4][2];
  for (int i = 0; i < 4; i++)
    for (int j = 0; j < 2; j++) acc[i][j] = (f32x4){0.f, 0.f, 0.f, 0.f};

  for (int kb = 0; kb < 512; kb += 64) {
    __syncthreads();
    // ---- stage A via gload_lds: 1024 units (row,pos), 2 per thread
    for (int i = 0; i < 2; i++) {
      int grp = w + i * 8;
      int unit = grp * 64 + lane;
      int row = unit >> 3, pos = unit & 7;
      int j = pos ^ (row & 7);
      gload16(&Wh[(Mb + row) * 512 + kb + j * 8], &sm[grp * 512]);
    }
    // ---- stage B: 8 float2 (8 k-rows x 2 n), pack, 2 b128 swizzled writes
    {
      float2 fB[8];
      for (int rr = 0; rr < 8; rr++)
        fB[rr] = *(const float2*)&x[(b * 512 + kb + kg8 * 8 + rr) * 1024 +
                                    Nb + n0];
      short* Bt = sm + 8192;
      u32x4 wE = (u32x4){pkh(fB[0].x, fB[1].x), pkh(fB[2].x, fB[3].x),
                         pkh(fB[4].x, fB[5].x), pkh(fB[6].x, fB[7].x)};
      u32x4 wO = (u32x4){pkh(fB[0].y, fB[1].y), pkh(fB[2].y, fB[3].y),
                         pkh(fB[4].y, fB[5].y), pkh(fB[6].y, fB[7].y)};
      int offE = n0 * 64 + 8 * (kg8 ^ (n0 & 7));
      int offO = (n0 + 1) * 64 + 8 * (kg8 ^ ((n0 + 1) & 7));
      int o1 = swp ? offO : offE, o2 = swp ? offE : offO;
      u32x4 d1 = swp ? wO : wE, d2 = swp ? wE : wO;
      *(u32x4*)&Bt[o1] = d1;
      *(u32x4*)&Bt[o2] = d2;
    }
    __syncthreads();

    // ---- fragments + MFMA
    const short* Bt = sm + 8192;
    for (int ks = 0; ks < 2; ks++) {
      f16x8 af[4], bf[2];
      for (int mt = 0; mt < 4; mt++) {
        int o = wm * 64 + mt * 16 + ln;
        af[mt] = *(const f16x8*)&sm[o * 64 + 8 * ((ks * 4 + g) ^ (o & 7))];
      }
      for (int nt = 0; nt < 2; nt++) {
        int n = wn * 32 + nt * 16 + ln;
        bf[nt] = *(const f16x8*)&Bt[n * 64 + 8 * ((ks * 4 + g) ^ (n & 7))];
      }
      __builtin_amdgcn_s_setprio(1);
      for (int mt = 0; mt < 4; mt++)
        for (int nt = 0; nt < 2; nt++)
          acc[mt][nt] = MFMAH(af[mt], bf[nt], acc[mt][nt]);
      __builtin_amdgcn_s_setprio(0);
    }
  }

  // ---- epilogue: 2 n-passes of 64 (pass p: waves with wn>>1 == p write)
  unsigned* smU = (unsigned*)sm;
  for (int p = 0; p < 2; p++) {
    __syncthreads();
    if ((wn >> 1) == p) {
      if (mblk < 2) {
        // q/k: LDS [nl][o/2] u32 (2 fp16), stride 66 u32
        for (int mt = 0; mt < 4; mt++)
          for (int nt = 0; nt < 2; nt++) {
            float y0 = acc[mt][nt][0] + bfv[Mb + wm * 64 + mt * 16 + g * 4 + 0];
            float y1 = acc[mt][nt][1] + bfv[Mb + wm * 64 + mt * 16 + g * 4 + 1];
            float y2 = acc[mt][nt][2] + bfv[Mb + wm * 64 + mt * 16 + g * 4 + 2];
            float y3 = acc[mt][nt][3] + bfv[Mb + wm * 64 + mt * 16 + g * 4 + 3];
            u32x2 pk = (u32x2){pkh(y0, y1), pkh(y2, y3)};
            int nl = (wn & 1) * 32 + nt * 16 + ln;
            *(u32x2*)&smU[nl * 66 + wm * 32 + mt * 8 + g * 2] = pk;
          }
      } else {
        // v: LDS [o][nl] fp16, stride 72 shorts
        for (int mt = 0; mt < 4; mt++)
          for (int nt = 0; nt < 2; nt++)
            for (int r = 0; r < 4; r++) {
              int o = wm * 64 + mt * 16 + g * 4 + r;
              sm[o * 72 + (wn & 1) * 32 + nt * 16 + ln] =
                  f2h(acc[mt][nt][r] + bfv[Mb + o]);
            }
      }
    }
    __syncthreads();
    if (mblk < 2) {
      unsigned short* dh = (mblk == 0) ? qH : kH;
      for (int it = 0; it < 2; it++) {
        int task = it * 512 + t;
        int h = task >> 8, nl = (task >> 2) & 63, qc = task & 3;
        u32x4 v4 = *(const u32x4*)&smU[nl * 66 + h * 16 + qc * 4];
        int gi = ((b * 4 + h) * 1024 + Nb + p * 64 + nl) * 32 + qc * 8;
        *(u32x4*)&dh[gi] = v4;
      }
    } else {
      int bh = b * 4 + (mblk - 2);
      for (int it = 0; it < 2; it++) {
        int task = it * 512 + t;
        int o = task >> 3, qc = task & 7;
        u32x4 vv = *(const u32x4*)&sm[o * 72 + qc * 8];
        *(u32x4*)&vH[(bh * 128 + o) * 1024 + Nb + p * 64 + qc * 8] = vv;
      }
    }
  }
}

// ---------------------------------------------------------------------------
// Flash attention (unchanged from round 8/10/11 — validated).
// ---------------------------------------------------------------------------
__global__ __launch_bounds__(512, 4) void attn_kernel(
    const float* __restrict__ x,
    const unsigned short* __restrict__ qH, const unsigned short* __restrict__ kH,
    const unsigned short* __restrict__ posH, const unsigned short* __restrict__ vH,
    float* __restrict__ out)
{
  __shared__ __align__(16) short sm[2 * 12288 + 8 * 1152];  // 67584 B

  int bid = blockIdx.x;
  int bh = (bid & 7) * 8 + ((bid >> 3) & 7);
  int qt = bid >> 6;
  int b = bh >> 2, h = bh & 3;
  int t = threadIdx.x;
  int lane = t & 63, w = t >> 6, ln = lane & 15, g = (lane >> 4) & 3;

  int qrow = qt * 128 + w * 16 + ln;
  f16x8 bQ   = *(const f16x8*)&qH[(bh * 1024 + qrow) * 32 + g * 8];
  f16x8 bPos = *(const f16x8*)&posH[(h * 1024 + qrow) * 32 + g * 8];

  f16x8 aOnes;
  {
    _Float16 o1 = (ln == 0) ? (_Float16)1.0f : (_Float16)0.0f;
    for (int i = 0; i < 8; i++) aOnes[i] = o1;
  }

  f32x4 acc[9];  // [0..7] = output channels, [8] = l row-sum (m=0 row)
  for (int ct = 0; ct < 9; ct++) acc[ct] = (f32x4){0.f, 0.f, 0.f, 0.f};
  float m_run = -1e30f;

  short* Pw = &sm[24576 + w * 1152];

  auto STAGE = [&](int bb, int jb) {
    {
      int u = t & 255;
      int r = u >> 2;
      int ch = (u & 3) ^ (r & 3) ^ ((r >> 2) & 3);
      long gq = (long)(bh * 1024 + jb + r) * 32 + ch * 8;
      const unsigned short* src = (t < 256) ? kH : qH;
      short* base = &sm[bb * 12288 + ((t < 256) ? 0 : 2048) + (w & 3) * 512];
      gload16(&src[gq], base);
    }
    for (int i = 0; i < 2; i++) {
      int u = t + i * 512;
      int c = u >> 3;
      int vch = (u & 7) ^ (c & 7);
      long gv = (long)(bh * 128 + c) * 1024 + jb + vch * 8;
      short* base = &sm[bb * 12288 + 4096 + (w + i * 8) * 512];
      gload16(&vH[gv], base);
    }
  };

  STAGE(0, 0);

  for (int it = 0; it < 16; ++it) {
    int cur = it & 1;
    if (it < 15) {
      STAGE(cur ^ 1, (it + 1) * 64);
      asm volatile("s_waitcnt vmcnt(3)" ::: "memory");
    } else {
      asm volatile("s_waitcnt vmcnt(0)" ::: "memory");
    }
    __builtin_amdgcn_s_barrier();
    __builtin_amdgcn_sched_barrier(0);

    const short* B = &sm[cur * 12288];

    f16x8 aK[4], aQ[4];
    for (int kt = 0; kt < 4; kt++) {
      int r = kt * 16 + ln;
      int p = g ^ (r & 3) ^ ((r >> 2) & 3);
      int off = r * 32 + p * 8;
      aK[kt] = *(const f16x8*)&B[off];
      aQ[kt] = *(const f16x8*)&B[2048 + off];
    }

    f32x4 s[4];
    for (int kt = 0; kt < 4; kt++) s[kt] = (f32x4){0.f, 0.f, 0.f, 0.f};
    __builtin_amdgcn_s_setprio(1);
    for (int kt = 0; kt < 4; kt++) s[kt] = MFMAH(aK[kt], bQ, s[kt]);
    for (int kt = 0; kt < 4; kt++) s[kt] = MFMAH(aQ[kt], bPos, s[kt]);
    __builtin_amdgcn_s_setprio(0);

    float m0 = fmaxf(fmaxf(s[0][0], s[0][1]), fmaxf(s[0][2], s[0][3]));
    float m1 = fmaxf(fmaxf(s[1][0], s[1][1]), fmaxf(s[1][2], s[1][3]));
    float m2 = fmaxf(fmaxf(s[2][0], s[2][1]), fmaxf(s[2][2], s[2][3]));
    float m3 = fmaxf(fmaxf(s[3][0], s[3][1]), fmaxf(s[3][2], s[3][3]));
    float mx = fmaxf(fmaxf(m0, m1), fmaxf(m2, m3));
    if (__any(mx > m_run + 8.f)) {
      float mxf = fmaxf(mx, __shfl_xor(mx, 16));
      mxf = fmaxf(mxf, __shfl_xor(mxf, 32));
      float mnew = fmaxf(m_run, mxf);
      float scl = __builtin_amdgcn_exp2f(m_run - mnew);
      for (int ct = 0; ct < 9; ct++) acc[ct] *= scl;
      m_run = mnew;
    }
    for (int kt = 0; kt < 4; kt++)
      for (int r = 0; r < 4; r++)
        s[kt][r] = __builtin_amdgcn_exp2f(s[kt][r] - m_run);

    for (int kt = 0; kt < 4; kt++) {
      u32x2 pk = (u32x2){pkh(s[kt][0], s[kt][1]), pkh(s[kt][2], s[kt][3])};
      *(u32x2*)&Pw[ln * 72 + kt * 16 + g * 4] = pk;
    }
    asm volatile("s_waitcnt lgkmcnt(0)" ::: "memory");
    __builtin_amdgcn_sched_barrier(0);
    f16x8 pFrag[2];
    for (int st2 = 0; st2 < 2; st2++)
      pFrag[st2] = *(const f16x8*)&Pw[ln * 72 + st2 * 32 + g * 8];

    __builtin_amdgcn_s_setprio(1);
    for (int ct = 0; ct < 8; ct++)
      for (int st2 = 0; st2 < 2; st2++) {
        int c = ct * 16 + ln;
        int pos = (st2 * 4 + g) ^ (c & 7);
        f16x8 av = *(const f16x8*)&B[4096 + c * 64 + pos * 8];
        acc[ct] = MFMAH(av, pFrag[st2], acc[ct]);
      }
    acc[8] = MFMAH(aOnes, pFrag[0], acc[8]);
    acc[8] = MFMAH(aOnes, pFrag[1], acc[8]);
    __builtin_amdgcn_s_setprio(0);

    __builtin_amdgcn_sched_barrier(0);
    __builtin_amdgcn_s_barrier();
    __builtin_amdgcn_sched_barrier(0);
  }

  float lsum = __shfl(acc[8][0], ln);
  float inv = 1.0f / lsum;
  int m = qt * 128 + w * 16 + ln;
  for (int ct = 0; ct < 8; ct++)
    for (int r = 0; r < 4; r++) {
      int c = h * 128 + ct * 16 + g * 4 + r;
      int gi = (b * 512 + c) * 1024 + m;
      out[gi] = acc[ct][r] * inv + x[gi];
    }
}

// ---------------------------------------------------------------------------
extern "C" void kernel_launch(void* const* d_in, const int* in_sizes, int n_in,
                              void* d_out, int out_size, void* d_ws, size_t ws_size,
                              hipStream_t stream) {
  const float* x    = (const float*)d_in[0];
  const float* Wq   = (const float*)d_in[1];
  const float* bq   = (const float*)d_in[2];
  const float* qg   = (const float*)d_in[3];
  const float* qbe  = (const float*)d_in[4];
  const float* qme  = (const float*)d_in[5];
  const float* qva  = (const float*)d_in[6];
  const float* Wk   = (const float*)d_in[7];
  const float* bk   = (const float*)d_in[8];
  const float* kg   = (const float*)d_in[9];
  const float* kbe  = (const float*)d_in[10];
  const float* kme  = (const float*)d_in[11];
  const float* kva  = (const float*)d_in[12];
  const float* Wv   = (const float*)d_in[13];
  const float* bv   = (const float*)d_in[14];
  const float* vg   = (const float*)d_in[15];
  const float* vbe  = (const float*)d_in[16];
  const float* vme  = (const float*)d_in[17];
  const float* vva  = (const float*)d_in[18];
  const float* relh = (const float*)d_in[19];
  const float* relw = (const float*)d_in[20];
  float* outp = (float*)d_out;

  unsigned char* ws = (unsigned char*)d_ws;
  unsigned short* Whp  = (unsigned short*)(ws + 0);        // 768*512*2
  float*          bfv  = (float*)(ws + 786432);            // 768*4
  unsigned short* qHp  = (unsigned short*)(ws + 789504);   // 64*1024*32*2
  unsigned short* kHp  = (unsigned short*)(ws + 4983808);
  unsigned short* posHp= (unsigned short*)(ws + 9178112);  // 4*1024*32*2
  unsigned short* vHp  = (unsigned short*)(ws + 9440256);  // 64*128*1024*2
  // total ws used: 26,217,472 bytes

  setup_kernel<<<2048, 256, 0, stream>>>(Wq, bq, qg, qbe, qme, qva,
                                         Wk, bk, kg, kbe, kme, kva,
                                         Wv, bv, vg, vbe, vme, vva,
                                         relh, relw, Whp, bfv, posHp);
  proj_kernel<<<768, 512, 0, stream>>>(x, Whp, bfv, qHp, kHp, vHp);
  attn_kernel<<<512, 512, 0, stream>>>(x, qHp, kHp, posHp, vHp, outp);
}